// Round 4
// baseline (712.273 us; speedup 1.0000x reference)
//
#include <hip/hip_runtime.h>
#include <math.h>

typedef short  bf16x8 __attribute__((ext_vector_type(8)));
typedef float  f32x4  __attribute__((ext_vector_type(4)));
typedef float  f32x2  __attribute__((ext_vector_type(2)));

#define DIM   1024
#define RANK  256
#define NROWS 16
#define NT    512
#define NWAVE 8
#define TOTAL_ROWS 4096
#define OUT_HALF (TOTAL_ROWS*DIM)

// LDS byte layout
#define VS_OFF   0            // ushort[16][1024], XOR-swizzled rows (32768)
#define H2_OFF   32768        // ushort[16][256],  XOR-swizzled rows (8192)
#define RING_OFF 40960        // 8 waves x 8 KB ring (65536)
#define GS_OFF   106496       // ushort[16][1032]  pitch 2064 B (33024)
#define GS_PITCH 2064
#define WS_OFF   139520       // float[16][8] (512)
#define SG_OFF   140032       // float[16]    (64)
#define SMEM_BYTES 140096

static constexpr double XI  = 0.1786178958448091;
static constexpr double LAM = -0.2123418310626054;
static constexpr double CHI = -0.0662645826698185;

typedef __attribute__((address_space(1))) void as1_void;
typedef __attribute__((address_space(3))) void as3_void;

#define WAITV(n) asm volatile("s_waitcnt vmcnt(" #n ")" ::: "memory")
#define BAR() do { asm volatile("s_waitcnt lgkmcnt(0)" ::: "memory"); \
                   __builtin_amdgcn_s_barrier(); \
                   asm volatile("" ::: "memory"); } while (0)

__device__ __forceinline__ unsigned short f2bf(float f) {
    unsigned u = __builtin_bit_cast(unsigned, f);
    u += 0x7FFFu + ((u >> 16) & 1u);        // round-to-nearest-even
    return (unsigned short)(u >> 16);
}
__device__ __forceinline__ float bf2f(unsigned short b) {
    return __builtin_bit_cast(float, ((unsigned)b) << 16);
}

// swizzle: byte ^= (row&7)<<4 -> 16 A-rows spread over 8 16B slots
__device__ __forceinline__ int vs_addr(int m, int kb) {
    return VS_OFF + ((m * 2048 + kb) ^ ((m & 7) << 4));
}
__device__ __forceinline__ int h2_addr(int m, int kb) {
    return H2_OFF + ((m * 512 + kb) ^ ((m & 7) << 4));
}

// micro-stage u (0..134) -> pk fragment index (1 KB units), minus wave part.
// H (u%128 < 64): frag = (ks*16) + (u&1)  [+ w*2],  ks = (u%128)>>1
// G (u%128 >=64): frag = 512 + kk*64 + p*4 + i [+ w*8]
__device__ __forceinline__ int frag_const(int u) {
    int uu = (u >= 128) ? (u - 128) : u;
    if (uu < 64) return ((uu >> 1) * 16) + (uu & 1);
    int g = uu - 64;
    int kk = (g >> 2) & 7, p = g >> 5, i = g & 3;
    return 512 + kk * 64 + p * 4 + i;
}
__device__ __forceinline__ int frag_wmul(int u) {
    int uu = (u >= 128) ? (u - 128) : u;
    return (uu < 64) ? 2 : 8;
}

// ---- prep: pack U,W (fp32) into bf16 MFMA B-fragment order in d_ws ----
__global__ __launch_bounds__(256)
void prep_pack(const float* __restrict__ U, const float* __restrict__ Wm,
               bf16x8* __restrict__ pk)
{
    const int tid  = blockIdx.x * 256 + threadIdx.x;   // 0..65535
    const int lane = tid & 63;
    const int frag = tid >> 6;                          // 0..1023
    bf16x8 o;
    if (frag < 512) {
        const int kt = frag >> 4, nt = frag & 15;
        const int krow = kt * 32 + (lane >> 4) * 8;
        const int n    = nt * 16 + (lane & 15);
        #pragma unroll
        for (int j = 0; j < 8; ++j) o[j] = (short)f2bf(U[(krow + j) * RANK + n]);
    } else {
        const int f = frag - 512;
        const int kt = f >> 6, nt = f & 63;
        const int krow = kt * 32 + (lane >> 4) * 8;
        const int n    = nt * 16 + (lane & 15);
        #pragma unroll
        for (int j = 0; j < 8; ++j) o[j] = (short)f2bf(Wm[(krow + j) * DIM + n]);
    }
    pk[frag * 64 + lane] = o;
}

__global__ __launch_bounds__(NT, 2)
void omelyan_mfma(const float* __restrict__ x_in,
                  const float* __restrict__ v_in,
                  const float* __restrict__ force,
                  const float* __restrict__ Vw,
                  const int* __restrict__ steps_p,
                  const bf16x8* __restrict__ pk,
                  float* __restrict__ out)
{
    extern __shared__ char smem[];
    float* wsums = (float*)(smem + WS_OFF);
    float* sings = (float*)(smem + SG_OFF);

    const int t    = threadIdx.x;        // 0..511
    const int lane = t & 63;
    const int w    = t >> 6;             // 0..7
    const int row0 = blockIdx.x * NROWS;
    const int nsteps = steps_p[0];

    char* ringp = smem + RING_OFF + w * 8192;
    char* pkb   = (char*)pk;

    const float dt = 0.01f;

    // per-thread elementwise state: element (m, d = 2t+j), j=0,1
    float xr[NROWS][2], vr[NROWS][2], fr[NROWS][2];
    f32x2 vw = *(const f32x2*)&Vw[2 * t];

    #pragma unroll
    for (int m = 0; m < NROWS; ++m) {
        const int base = (row0 + m) * DIM + 2 * t;
        const f32x2 xv = *(const f32x2*)&x_in[base];
        const f32x2 vv = *(const f32x2*)&v_in[base];
        const f32x2 fv = *(const f32x2*)&force[base];
        xr[m][0] = xv[0]; xr[m][1] = xv[1];
        vr[m][0] = vv[0]; vr[m][1] = vv[1];
        fr[m][0] = fv[0]; fr[m][1] = fv[1];
        const unsigned p = (unsigned)f2bf(vv[0]) | ((unsigned)f2bf(vv[1]) << 16);
        *(unsigned*)(smem + vs_addr(m, 4 * t)) = p;
    }
    __syncthreads();   // real barrier: drains vmcnt to 0 -> clean counter base

#define ISSUE(u_) do { \
        const int fi_ = frag_const(u_) + w * frag_wmul(u_); \
        char* gp_ = pkb + fi_ * 1024 + lane * 16; \
        __builtin_amdgcn_global_load_lds((as1_void*)gp_, \
            (as3_void*)(ringp + (((u_) & 7) * 1024)), 16, 0, 0); \
    } while (0)

    // pipeline prologue: issue micros 0..6, preload frag 0 into bregA
    bf16x8 bregA, bregB, aregA, aregB;
    #pragma unroll
    for (int u = 0; u < 7; ++u) ISSUE(u);
    WAITV(6);
    bregA = *(const bf16x8*)(ringp + lane * 16);

    #pragma unroll 1
    for (int step = 0; step < nsteps; ++step) {
        #pragma unroll 1
        for (int sub = 0; sub < 4; ++sub) {
            const float cdt = dt * (sub == 0 ? (float)XI :
                                    sub == 1 ? (float)CHI :
                                    sub == 2 ? (float)(1.0 - 2.0 * (CHI + XI)) :
                                               (float)CHI);
            const float ddt = dt * ((sub == 0 || sub == 3)
                                    ? (float)((1.0 - 2.0 * LAM) * 0.5)
                                    : (float)LAM);

            // ---- drift x, r2 reduce ----
            #pragma unroll
            for (int m = 0; m < NROWS; ++m) {
                float s = 0.f;
                #pragma unroll
                for (int j = 0; j < 2; ++j) {
                    xr[m][j] = fmaf(cdt, vr[m][j], xr[m][j]);
                    s = fmaf(xr[m][j], xr[m][j], s);
                }
                #pragma unroll
                for (int off = 32; off >= 1; off >>= 1) s += __shfl_xor(s, off, 64);
                if (lane == 0) wsums[m * NWAVE + w] = s;
            }
            BAR();                                      // b1
            if (t < NROWS) {
                float r2 = 0.f;
                #pragma unroll
                for (int q = 0; q < NWAVE; ++q) r2 += wsums[t * NWAVE + q];
                sings[t] = 1.f + exp2f(-r2 * 1.4426950408889634f);
            }

            // ---- H: h = v @ U  (64 micros: ks=s>>1, nt=w*2+(s&1)) ----
            {
                aregA = *(const bf16x8*)(smem + vs_addr(lane & 15, (lane >> 4) * 16));
                f32x4 hacc0 = {0.f,0.f,0.f,0.f}, hacc1 = {0.f,0.f,0.f,0.f};
                #pragma unroll 64
                for (int s = 0; s < 64; ++s) {
                    WAITV(5);                            // frag s+1 landed
                    {   // prefetch B frag s+1 -> breg[(s+1)&1]
                        bf16x8 nb = *(const bf16x8*)(ringp + (((s + 1) & 7) * 1024) + lane * 16);
                        if ((s + 1) & 1) bregB = nb; else bregA = nb;
                    }
                    const int ks = s >> 1;
                    bf16x8 a = (ks & 1) ? aregB : aregA;
                    if (s & 1)
                        hacc1 = __builtin_amdgcn_mfma_f32_16x16x32_bf16(a, bregB, hacc1, 0, 0, 0);
                    else
                        hacc0 = __builtin_amdgcn_mfma_f32_16x16x32_bf16(a, bregA, hacc0, 0, 0, 0);
                    if ((s & 1) && ks < 31) {            // prefetch A(ks+1)
                        bf16x8 na = *(const bf16x8*)(smem + vs_addr(lane & 15, (ks + 1) * 64 + (lane >> 4) * 16));
                        if ((ks + 1) & 1) aregB = na; else aregA = na;
                    }
                    ISSUE(s + 7);
                }
                // h2 = (h*h) bf16, swizzled; D: col=lane&15, row=(lane>>4)*4+r
                #pragma unroll
                for (int r = 0; r < 4; ++r) {
                    const int m  = (lane >> 4) * 4 + r;
                    const int n0 = (w * 2 + 0) * 16 + (lane & 15);
                    const int n1 = (w * 2 + 1) * 16 + (lane & 15);
                    *(unsigned short*)(smem + h2_addr(m, 2 * n0)) = f2bf(hacc0[r] * hacc0[r]);
                    *(unsigned short*)(smem + h2_addr(m, 2 * n1)) = f2bf(hacc1[r] * hacc1[r]);
                }
            }
            BAR();                                      // b2

            // ---- G: gamma = h2 @ W (64 micros: kk=(sg>>2)&7, p=sg>>5, i=sg&3) ----
            {
                aregA = *(const bf16x8*)(smem + h2_addr(lane & 15, (lane >> 4) * 16));
                f32x4 g0 = {0.f,0.f,0.f,0.f}, g1 = {0.f,0.f,0.f,0.f};
                f32x4 g2 = {0.f,0.f,0.f,0.f}, g3 = {0.f,0.f,0.f,0.f};
                #pragma unroll 64
                for (int sg = 0; sg < 64; ++sg) {
                    WAITV(5);
                    {   // prefetch B frag (64+sg+1) -> breg[(sg+1)&1]
                        bf16x8 nb = *(const bf16x8*)(ringp + (((64 + sg + 1) & 7) * 1024) + lane * 16);
                        if ((sg + 1) & 1) bregB = nb; else bregA = nb;
                    }
                    const int kk = (sg >> 2) & 7;
                    const int i  = sg & 3;
                    bf16x8 a = (kk & 1) ? aregB : aregA;
                    bf16x8 b = (sg & 1) ? bregB : bregA;
                    if      (i == 0) g0 = __builtin_amdgcn_mfma_f32_16x16x32_bf16(a, b, g0, 0, 0, 0);
                    else if (i == 1) g1 = __builtin_amdgcn_mfma_f32_16x16x32_bf16(a, b, g1, 0, 0, 0);
                    else if (i == 2) g2 = __builtin_amdgcn_mfma_f32_16x16x32_bf16(a, b, g2, 0, 0, 0);
                    else             g3 = __builtin_amdgcn_mfma_f32_16x16x32_bf16(a, b, g3, 0, 0, 0);
                    if (i == 3 && sg < 63) {             // prefetch A(next kk)
                        const int nk = (kk + 1) & 7;
                        bf16x8 na = *(const bf16x8*)(smem + h2_addr(lane & 15, nk * 64 + (lane >> 4) * 16));
                        if (nk & 1) aregB = na; else aregA = na;
                    }
                    ISSUE(64 + sg + 7);
                    if (sg == 31) {                      // pass-0 gacc -> gs (bf16)
                        #pragma unroll
                        for (int r = 0; r < 4; ++r) {
                            const int m = (lane >> 4) * 4 + r;
                            const int cb = (w * 8) * 16 + (lane & 15);
                            *(unsigned short*)(smem + GS_OFF + m * GS_PITCH + (cb +  0) * 2) = f2bf(g0[r]);
                            *(unsigned short*)(smem + GS_OFF + m * GS_PITCH + (cb + 16) * 2) = f2bf(g1[r]);
                            *(unsigned short*)(smem + GS_OFF + m * GS_PITCH + (cb + 32) * 2) = f2bf(g2[r]);
                            *(unsigned short*)(smem + GS_OFF + m * GS_PITCH + (cb + 48) * 2) = f2bf(g3[r]);
                        }
                        g0 = (f32x4){0.f,0.f,0.f,0.f}; g1 = (f32x4){0.f,0.f,0.f,0.f};
                        g2 = (f32x4){0.f,0.f,0.f,0.f}; g3 = (f32x4){0.f,0.f,0.f,0.f};
                    }
                }
                // pass-1 gacc -> gs
                #pragma unroll
                for (int r = 0; r < 4; ++r) {
                    const int m = (lane >> 4) * 4 + r;
                    const int cb = (w * 8 + 4) * 16 + (lane & 15);
                    *(unsigned short*)(smem + GS_OFF + m * GS_PITCH + (cb +  0) * 2) = f2bf(g0[r]);
                    *(unsigned short*)(smem + GS_OFF + m * GS_PITCH + (cb + 16) * 2) = f2bf(g1[r]);
                    *(unsigned short*)(smem + GS_OFF + m * GS_PITCH + (cb + 32) * 2) = f2bf(g2[r]);
                    *(unsigned short*)(smem + GS_OFF + m * GS_PITCH + (cb + 48) * 2) = f2bf(g3[r]);
                }
            }
            BAR();                                      // b3

            // ---- kick: v += ddt*(force - gamma*gate*sing); refresh vs ----
            #pragma unroll
            for (int m = 0; m < NROWS; ++m) {
                const unsigned gu = *(const unsigned*)(smem + GS_OFF + m * GS_PITCH + 4 * t);
                const float gL = bf2f((unsigned short)(gu & 0xFFFFu));
                const float gH = bf2f((unsigned short)(gu >> 16));
                const float sing = sings[m];
                unsigned pp = 0;
                #pragma unroll
                for (int j = 0; j < 2; ++j) {
                    const float g  = j ? gH : gL;
                    const float z  = xr[m][j] * vw[j];
                    const float e  = exp2f(z * 2.885390081777927f);   // e^(2z)
                    const float th = 1.f - 2.f / (e + 1.f);           // tanh(z)
                    const float gate = fmaf(0.1f, th, 1.f);
                    const float a = fr[m][j] - g * gate * sing;
                    vr[m][j] = fmaf(ddt, a, vr[m][j]);
                    pp |= ((unsigned)f2bf(vr[m][j])) << (16 * j);
                }
                *(unsigned*)(smem + vs_addr(m, 4 * t)) = pp;
            }
            BAR();                                      // b4
        } // sub

        // final drift: x += C5*dt*v
        const float c5dt = dt * (float)XI;
        #pragma unroll
        for (int m = 0; m < NROWS; ++m)
            #pragma unroll
            for (int j = 0; j < 2; ++j)
                xr[m][j] = fmaf(c5dt, vr[m][j], xr[m][j]);
    } // step

    // ---- store (x, v) ----
    #pragma unroll
    for (int m = 0; m < NROWS; ++m) {
        const int base = (row0 + m) * DIM + 2 * t;
        f32x2 xo, vo;
        xo[0] = xr[m][0]; xo[1] = xr[m][1];
        vo[0] = vr[m][0]; vo[1] = vr[m][1];
        *(f32x2*)&out[base] = xo;
        *(f32x2*)&out[OUT_HALF + base] = vo;
    }
#undef ISSUE
}

extern "C" void kernel_launch(void* const* d_in, const int* in_sizes, int n_in,
                              void* d_out, int out_size, void* d_ws, size_t ws_size,
                              hipStream_t stream) {
    const float* x_in  = (const float*)d_in[0];
    const float* v_in  = (const float*)d_in[1];
    const float* force = (const float*)d_in[2];
    const float* Umat  = (const float*)d_in[3];
    const float* Wmat  = (const float*)d_in[4];
    const float* Vw    = (const float*)d_in[5];
    const int*   steps = (const int*)d_in[6];
    float* out = (float*)d_out;
    bf16x8* pk = (bf16x8*)d_ws;   // 1 MiB

    (void)hipFuncSetAttribute((const void*)omelyan_mfma,
                              hipFuncAttributeMaxDynamicSharedMemorySize,
                              SMEM_BYTES);

    prep_pack<<<dim3(256), dim3(256), 0, stream>>>(Umat, Wmat, pk);
    omelyan_mfma<<<dim3(TOTAL_ROWS / NROWS), dim3(NT), SMEM_BYTES, stream>>>(
        x_in, v_in, force, Vw, steps, pk, out);
}